// Round 3
// baseline (538.845 us; speedup 1.0000x reference)
//
#include <hip/hip_runtime.h>
#include <hip/hip_bf16.h>

// Problem sizes (fixed by reference): B=8, N=20, T=300, U=64, H=512, NT=6000
#define BB 8
#define NN 20
#define TT 300
#define UU 64
#define HH 512
#define NT 6000

// ws layout (floats) — 3,616,769 floats ≈ 14.5 MB total:
//  scores : [B][NT][U]   off 0          (3,072,000)  raw scores, overwritten in-place
//                                                    with attn by k2 AFTER k2b/k3 run
//  tmax   : [B][U][N]    off 3,072,000  (10,240)
//  tsum   : [B][U][N]    off 3,082,240  (10,240)
//  W      : [B][U][1024] off 3,092,480  (524,288)    [0:512]=q f32, [512:1024]=aggdoc
//  flag   : int          off 3,616,768  (1)          1 = inputs are f32, 0 = bf16
//
// Order: kdetect, k0, k1(scores), k2b(t-stats), k3(aggdoc), k2(in-place U-softmax), k4(out)

__device__ __forceinline__ float bf2f(unsigned short u) {
  union { unsigned int i; float f; } c; c.i = ((unsigned int)u) << 16; return c.f;
}
__device__ __forceinline__ unsigned short f2bf(float f) {
  union { float f; unsigned int i; } c; c.f = f;
  unsigned int u = c.i;
  unsigned int r = (u + 0x7fffu + ((u >> 16) & 1u)) >> 16;  // RNE
  return (unsigned short)r;
}

// ---------------- detect: are inputs f32 (1) or bf16 (0)? ----------------
// bf16 N(0,1) data: exponent in ~[110,140]. f32 data: every other ushort is
// mantissa garbage with uniform exponent -> ~45% of ushorts look "weird".
__global__ __launch_bounds__(256) void kdetect(const unsigned short* __restrict__ d16,
                                               int* __restrict__ flag) {
  __shared__ int cnt[4];
  int t = threadIdx.x;
  unsigned short v = d16[t];
  int e = (v >> 7) & 0xFF;
  int weird = (e > 140 || (e < 110 && (v & 0x7FFFu) != 0)) ? 1 : 0;
  unsigned long long m = __ballot(weird);
  if ((t & 63) == 0) cnt[t >> 6] = __popcll(m);
  __syncthreads();
  if (t == 0) flag[0] = (cnt[0] + cnt[1] + cnt[2] + cnt[3] >= 32) ? 1 : 0;
}

// ---------------- K0: init W (q as f32, zero aggdoc half) ----------------
__global__ __launch_bounds__(256) void k0_init(const void* __restrict__ qv,
                                               const int* __restrict__ flag,
                                               float* __restrict__ W) {
  const int isf32 = *flag;
  int idx = blockIdx.x * 256 + threadIdx.x;  // B*U*1024 = 524288
  int h2 = idx & 1023;
  int bu = idx >> 10;
  float v = 0.0f;
  if (h2 < HH) {
    v = isf32 ? ((const float*)qv)[bu * HH + h2]
              : bf2f(((const unsigned short*)qv)[bu * HH + h2]);
  }
  W[idx] = v;
}

// ---------------- K1: scores[b,k,u] = sum_h doc[b,k,h]*q[b,u,h] ----------------
__global__ __launch_bounds__(256) void k1_scores(const void* __restrict__ docv,
                                                 const void* __restrict__ qv,
                                                 const int* __restrict__ flag,
                                                 float* __restrict__ scores) {
  __shared__ float sA[64][68];
  __shared__ float sB[64][68];
  const int isf32 = *flag;
  const int b = blockIdx.y;
  const int kt = blockIdx.x;  // 0..93
  const int tid = threadIdx.x;
  const int tu = tid & 15, tk = tid >> 4;
  float acc[4][4] = {};
  const int kmax = NT - kt * 64;  // valid rows in this tile
  const size_t arow0 = (size_t)b * NT * HH + (size_t)kt * 64 * HH;
  const size_t brow0 = (size_t)b * UU * HH;
  for (int c = 0; c < 8; ++c) {
    const int h0 = c * 64;
    // stage 64 rows x 64 f32: 1024 float4-groups
#pragma unroll
    for (int i = 0; i < 4; ++i) {
      int g = tid + 256 * i;
      int row = g >> 4, c4 = (g & 15) * 4;
      float4 va = make_float4(0.f, 0.f, 0.f, 0.f), vb;
      if (isf32) {
        const float* df = (const float*)docv;
        const float* qf = (const float*)qv;
        if (row < kmax) va = *(const float4*)(df + arow0 + (size_t)row * HH + h0 + c4);
        vb = *(const float4*)(qf + brow0 + (size_t)row * HH + h0 + c4);
      } else {
        const unsigned short* db = (const unsigned short*)docv;
        const unsigned short* qb = (const unsigned short*)qv;
        if (row < kmax) {
          ushort4 t4 = *(const ushort4*)(db + arow0 + (size_t)row * HH + h0 + c4);
          va = make_float4(bf2f(t4.x), bf2f(t4.y), bf2f(t4.z), bf2f(t4.w));
        }
        ushort4 t4 = *(const ushort4*)(qb + brow0 + (size_t)row * HH + h0 + c4);
        vb = make_float4(bf2f(t4.x), bf2f(t4.y), bf2f(t4.z), bf2f(t4.w));
      }
      *(float4*)&sA[row][c4] = va;
      *(float4*)&sB[row][c4] = vb;
    }
    __syncthreads();
#pragma unroll 2
    for (int hh = 0; hh < 64; hh += 4) {
      float4 a4[4], b4[4];
#pragma unroll
      for (int i = 0; i < 4; ++i) a4[i] = *(const float4*)&sA[tk * 4 + i][hh];
#pragma unroll
      for (int j = 0; j < 4; ++j) b4[j] = *(const float4*)&sB[tu * 4 + j][hh];
#pragma unroll
      for (int i = 0; i < 4; ++i)
#pragma unroll
        for (int j = 0; j < 4; ++j)
          acc[i][j] += a4[i].x * b4[j].x + a4[i].y * b4[j].y +
                       a4[i].z * b4[j].z + a4[i].w * b4[j].w;
    }
    __syncthreads();
  }
  const int k0 = kt * 64 + tk * 4;
#pragma unroll
  for (int i = 0; i < 4; ++i) {
    int k = k0 + i;
    if (k < NT) {
      float4 v = make_float4(acc[i][0], acc[i][1], acc[i][2], acc[i][3]);
      *(float4*)&scores[((size_t)b * NT + k) * 64 + tu * 4] = v;
    }
  }
}

// ---------------- K2b: per-(b,u,n) online max/sum over T with doc_mask ----------------
__global__ __launch_bounds__(256) void k2b_tstats(const float* __restrict__ scores,
                                                  const int* __restrict__ dm,
                                                  float* __restrict__ tmax,
                                                  float* __restrict__ tsum) {
  const int b = blockIdx.x / NN;
  const int n = blockIdx.x % NN;
  const int u = threadIdx.x & 63;
  const int tg = threadIdx.x >> 6;  // 0..3
  float m = -__builtin_inff(), s = 0.0f;
  for (int t = tg; t < TT; t += 4) {
    int dmv = dm[(b * NN + n) * TT + t];  // wave-uniform
    if (dmv) {
      float v = scores[((size_t)(b * NT) + n * TT + t) * 64 + u];
      if (v > m) { s = s * __expf(m - v) + 1.0f; m = v; }
      else s += __expf(v - m);
    }
  }
  __shared__ float sm[4][64], ss[4][64];
  sm[tg][u] = m; ss[tg][u] = s;
  __syncthreads();
  if (threadIdx.x < 64) {
    float M = sm[0][u];
#pragma unroll
    for (int i = 1; i < 4; ++i) M = fmaxf(M, sm[i][u]);
    float S = 0.0f;
#pragma unroll
    for (int i = 0; i < 4; ++i) {
      if (ss[i][u] > 0.0f) S += ss[i][u] * __expf(sm[i][u] - M);
    }
    tmax[(b * 64 + u) * NN + n] = M;
    tsum[(b * 64 + u) * NN + n] = S;
  }
}

// ---------------- K3: aggdoc[b,u,h] += sum_k p(b,u,k)*doc[b,k,h] into W[:,512:] ----------------
__global__ __launch_bounds__(256) void k3_aggdoc(const float* __restrict__ scores,
                                                 const void* __restrict__ docv,
                                                 const int* __restrict__ dm,
                                                 const float* __restrict__ tmax,
                                                 const float* __restrict__ tsum,
                                                 const int* __restrict__ flag,
                                                 float* __restrict__ W) {
  __shared__ float wL[32][68];
  __shared__ float dL[32][68];
  const int isf32 = *flag;
  const int b = blockIdx.z, hc = blockIdx.y, kc = blockIdx.x;  // (16,8,8) grid
  const int tid = threadIdx.x;
  const int th = tid & 15, tuq = tid >> 4;  // h = hc*64 + th*4 + j, u = tuq*4 + i
  float acc[4][4] = {};
  const int k0base = kc * 375, kend = k0base + 375;
  for (int k0 = k0base; k0 < kend; k0 += 32) {
    const int kn = min(32, kend - k0);
    // stage t-softmax weights: w[kk][uu]
#pragma unroll
    for (int i = 0; i < 8; ++i) {
      int idx = tid + 256 * i;  // 2048
      int kk = idx >> 6, uu = idx & 63;
      float w = 0.0f;
      if (kk < kn) {
        int k = k0 + kk;
        int n = k / TT, t = k - n * TT;
        if (dm[(b * NN + n) * TT + t]) {
          float S = tsum[(b * 64 + uu) * NN + n];
          if (S > 0.0f) {
            float M = tmax[(b * 64 + uu) * NN + n];
            w = __expf(scores[((size_t)(b * NT) + k) * 64 + uu] - M) / S;
          }
        }
      }
      wL[kk][uu] = w;
    }
    // stage doc chunk: [32][64] f32
#pragma unroll
    for (int i = 0; i < 2; ++i) {
      int g = tid + 256 * i;  // 512 groups of 4
      int kk = g >> 4, c4 = (g & 15) * 4;
      float4 v = make_float4(0.f, 0.f, 0.f, 0.f);
      if (kk < kn) {
        int k = k0 + kk;
        size_t off = ((size_t)(b * NT) + k) * HH + hc * 64 + c4;
        if (isf32) v = *(const float4*)((const float*)docv + off);
        else {
          ushort4 t4 = *(const ushort4*)((const unsigned short*)docv + off);
          v = make_float4(bf2f(t4.x), bf2f(t4.y), bf2f(t4.z), bf2f(t4.w));
        }
      }
      *(float4*)&dL[kk][c4] = v;
    }
    __syncthreads();
    for (int kk = 0; kk < kn; ++kk) {
      float4 w4 = *(const float4*)&wL[kk][tuq * 4];
      float4 d4 = *(const float4*)&dL[kk][th * 4];
      acc[0][0] += w4.x * d4.x; acc[0][1] += w4.x * d4.y; acc[0][2] += w4.x * d4.z; acc[0][3] += w4.x * d4.w;
      acc[1][0] += w4.y * d4.x; acc[1][1] += w4.y * d4.y; acc[1][2] += w4.y * d4.z; acc[1][3] += w4.y * d4.w;
      acc[2][0] += w4.z * d4.x; acc[2][1] += w4.z * d4.y; acc[2][2] += w4.z * d4.z; acc[2][3] += w4.z * d4.w;
      acc[3][0] += w4.w * d4.x; acc[3][1] += w4.w * d4.y; acc[3][2] += w4.w * d4.z; acc[3][3] += w4.w * d4.w;
    }
    __syncthreads();
  }
#pragma unroll
  for (int i = 0; i < 4; ++i) {
#pragma unroll
    for (int j = 0; j < 4; ++j) {
      size_t addr = ((size_t)(b * 64) + tuq * 4 + i) * 1024 + 512 + hc * 64 + th * 4 + j;
      atomicAdd(&W[addr], acc[i][j]);
    }
  }
}

// ---------------- K2: in-place restricted softmax over U with q_mask ----------------
__global__ __launch_bounds__(256) void k2_softmax_u(float* __restrict__ scores,
                                                    const int* __restrict__ qm) {
  const int row = blockIdx.x * 4 + (threadIdx.x >> 6);  // 0..47999
  const int u = threadIdx.x & 63;
  const int b = row / NT;
  const float s = scores[(size_t)row * 64 + u];
  const int m = qm[b * 64 + u];
  float v = m ? s : -__builtin_inff();
#pragma unroll
  for (int o = 32; o > 0; o >>= 1) v = fmaxf(v, __shfl_xor(v, o, 64));
  float e = m ? __expf(s - v) : 0.0f;
  float sum = e;
#pragma unroll
  for (int o = 32; o > 0; o >>= 1) sum += __shfl_xor(sum, o, 64);
  scores[(size_t)row * 64 + u] = (sum > 0.0f) ? (e / sum) : 0.0f;
}

// ---------------- K4: out[b,k,h2] = sum_u attn[b,k,u] * W[b,u,h2] ----------------
__global__ __launch_bounds__(256) void k4_out(const float* __restrict__ attn,
                                              const float* __restrict__ W,
                                              const int* __restrict__ flag,
                                              void* __restrict__ outv) {
  __shared__ float sAt[64][68];
  __shared__ float sWt[64][68];
  const int isf32 = *flag;
  const int b = blockIdx.z;
  const int kt = blockIdx.x;  // 0..93
  const int ht = blockIdx.y;  // 0..15
  const int tid = threadIdx.x;
  const int th2 = tid & 15, tkq = tid >> 4;
#pragma unroll
  for (int i = 0; i < 4; ++i) {
    int g = tid + 256 * i;  // 1024 float4 groups
    int row = g >> 4, c4 = (g & 15) * 4;
    int k = kt * 64 + row;
    float4 v = make_float4(0.f, 0.f, 0.f, 0.f);
    if (k < NT) v = *(const float4*)&attn[((size_t)(b * NT) + k) * 64 + c4];
    *(float4*)&sAt[row][c4] = v;
    float4 w = *(const float4*)&W[((size_t)(b * 64) + row) * 1024 + ht * 64 + c4];
    *(float4*)&sWt[row][c4] = w;
  }
  __syncthreads();
  float acc[4][4] = {};
#pragma unroll 4
  for (int u = 0; u < 64; u += 4) {
    float a[4][4];
#pragma unroll
    for (int i = 0; i < 4; ++i)
      *(float4*)a[i] = *(const float4*)&sAt[tkq * 4 + i][u];
#pragma unroll
    for (int r = 0; r < 4; ++r) {
      float4 w4 = *(const float4*)&sWt[u + r][th2 * 4];
#pragma unroll
      for (int i = 0; i < 4; ++i) {
        acc[i][0] += a[i][r] * w4.x;
        acc[i][1] += a[i][r] * w4.y;
        acc[i][2] += a[i][r] * w4.z;
        acc[i][3] += a[i][r] * w4.w;
      }
    }
  }
#pragma unroll
  for (int i = 0; i < 4; ++i) {
    int k = kt * 64 + tkq * 4 + i;
    if (k < NT) {
      size_t off = ((size_t)(b * NT) + k) * 1024 + ht * 64 + th2 * 4;
      if (isf32) {
        *(float4*)((float*)outv + off) =
            make_float4(acc[i][0], acc[i][1], acc[i][2], acc[i][3]);
      } else {
        ushort4 o;
        o.x = f2bf(acc[i][0]); o.y = f2bf(acc[i][1]);
        o.z = f2bf(acc[i][2]); o.w = f2bf(acc[i][3]);
        *(ushort4*)((unsigned short*)outv + off) = o;
      }
    }
  }
}

extern "C" void kernel_launch(void* const* d_in, const int* in_sizes, int n_in,
                              void* d_out, int out_size, void* d_ws, size_t ws_size,
                              hipStream_t stream) {
  const void* doc = d_in[0];            // [B][N][T][H]  f32 or bf16 (auto-detected)
  const void* q   = d_in[1];            // [B][U][H]     f32 or bf16
  const int* dmask = (const int*)d_in[2];  // int32 [B][N][T]
  const int* qmask = (const int*)d_in[3];  // int32 [B][U]

  float* ws = (float*)d_ws;
  float* scores = ws;                 // 3,072,000 floats (raw scores, then attn in-place)
  float* tmax   = ws + 3072000;       // 10,240
  float* tsum   = ws + 3082240;       // 10,240
  float* W      = ws + 3092480;       // 524,288
  int*   flag   = (int*)(ws + 3616768);

  kdetect<<<1, 256, 0, stream>>>((const unsigned short*)doc, flag);
  k0_init<<<2048, 256, 0, stream>>>(q, flag, W);
  k1_scores<<<dim3(94, 8), 256, 0, stream>>>(doc, q, flag, scores);
  k2b_tstats<<<160, 256, 0, stream>>>(scores, dmask, tmax, tsum);
  k3_aggdoc<<<dim3(16, 8, 8), 256, 0, stream>>>(scores, doc, dmask, tmax, tsum, flag, W);
  k2_softmax_u<<<12000, 256, 0, stream>>>(scores, qmask);
  k4_out<<<dim3(94, 16, 8), 256, 0, stream>>>(scores, W, flag, d_out);
}

// Round 4
// 509.456 us; speedup vs baseline: 1.0577x; 1.0577x over previous
//
#include <hip/hip_runtime.h>
#include <hip/hip_bf16.h>

// Problem sizes (fixed by reference): B=8, N=20, T=300, U=64, H=512, NT=6000
#define BB 8
#define NN 20
#define TT 300
#define UU 64
#define HH 512
#define NT 6000

// ws layout (float slots):
//  scores : [B][NT][U]   off 0          (3,072,000)  raw scores -> attn in-place (k2c/k2)
//  tmax   : [B][U][N]    off 3,072,000  (10,240)
//  tsum   : [B][U][N]    off 3,082,240  (10,240)
//  W      : [B][U][1024] off 3,092,480  (524,288)    [0:512]=q f32, [512:1024]=aggdoc
//  flag   : int          off 3,616,768  (4 slots reserved)
//  Pt     : bf16 [B][NT][U] off 3,616,772 (1,536,000 slots = 3,072,000 ushorts)
// total with Pt: 5,152,772 floats = 20.6 MB; without Pt: 14.5 MB (fallback path)

__device__ __forceinline__ float bf2f(unsigned short u) {
  union { unsigned int i; float f; } c; c.i = ((unsigned int)u) << 16; return c.f;
}
__device__ __forceinline__ unsigned short f2bf(float f) {
  union { float f; unsigned int i; } c; c.f = f;
  unsigned int u = c.i;
  unsigned int r = (u + 0x7fffu + ((u >> 16) & 1u)) >> 16;  // RNE
  return (unsigned short)r;
}

// ---------------- detect: are inputs f32 (1) or bf16 (0)? ----------------
__global__ __launch_bounds__(256) void kdetect(const unsigned short* __restrict__ d16,
                                               int* __restrict__ flag) {
  __shared__ int cnt[4];
  int t = threadIdx.x;
  unsigned short v = d16[t];
  int e = (v >> 7) & 0xFF;
  int weird = (e > 140 || (e < 110 && (v & 0x7FFFu) != 0)) ? 1 : 0;
  unsigned long long m = __ballot(weird);
  if ((t & 63) == 0) cnt[t >> 6] = __popcll(m);
  __syncthreads();
  if (t == 0) flag[0] = (cnt[0] + cnt[1] + cnt[2] + cnt[3] >= 32) ? 1 : 0;
}

// ---------------- K0: init W (q as f32, zero aggdoc half) ----------------
__global__ __launch_bounds__(256) void k0_init(const void* __restrict__ qv,
                                               const int* __restrict__ flag,
                                               float* __restrict__ W) {
  const int isf32 = *flag;
  int idx = blockIdx.x * 256 + threadIdx.x;  // B*U*1024 = 524288
  int h2 = idx & 1023;
  int bu = idx >> 10;
  float v = 0.0f;
  if (h2 < HH) {
    v = isf32 ? ((const float*)qv)[bu * HH + h2]
              : bf2f(((const unsigned short*)qv)[bu * HH + h2]);
  }
  W[idx] = v;
}

// ---------------- K1: scores[b,k,u] = sum_h doc[b,k,h]*q[b,u,h] ----------------
__global__ __launch_bounds__(256) void k1_scores(const void* __restrict__ docv,
                                                 const void* __restrict__ qv,
                                                 const int* __restrict__ flag,
                                                 float* __restrict__ scores) {
  __shared__ float sA[64][68];
  __shared__ float sB[64][68];
  const int isf32 = *flag;
  const int b = blockIdx.y;
  const int kt = blockIdx.x;  // 0..93
  const int tid = threadIdx.x;
  const int tu = tid & 15, tk = tid >> 4;
  float acc[4][4] = {};
  const int kmax = NT - kt * 64;
  const size_t arow0 = (size_t)b * NT * HH + (size_t)kt * 64 * HH;
  const size_t brow0 = (size_t)b * UU * HH;
  for (int c = 0; c < 8; ++c) {
    const int h0 = c * 64;
#pragma unroll
    for (int i = 0; i < 4; ++i) {
      int g = tid + 256 * i;
      int row = g >> 4, c4 = (g & 15) * 4;
      float4 va = make_float4(0.f, 0.f, 0.f, 0.f), vb;
      if (isf32) {
        const float* df = (const float*)docv;
        const float* qf = (const float*)qv;
        if (row < kmax) va = *(const float4*)(df + arow0 + (size_t)row * HH + h0 + c4);
        vb = *(const float4*)(qf + brow0 + (size_t)row * HH + h0 + c4);
      } else {
        const unsigned short* db = (const unsigned short*)docv;
        const unsigned short* qb = (const unsigned short*)qv;
        if (row < kmax) {
          ushort4 t4 = *(const ushort4*)(db + arow0 + (size_t)row * HH + h0 + c4);
          va = make_float4(bf2f(t4.x), bf2f(t4.y), bf2f(t4.z), bf2f(t4.w));
        }
        ushort4 t4 = *(const ushort4*)(qb + brow0 + (size_t)row * HH + h0 + c4);
        vb = make_float4(bf2f(t4.x), bf2f(t4.y), bf2f(t4.z), bf2f(t4.w));
      }
      *(float4*)&sA[row][c4] = va;
      *(float4*)&sB[row][c4] = vb;
    }
    __syncthreads();
#pragma unroll 2
    for (int hh = 0; hh < 64; hh += 4) {
      float4 a4[4], b4[4];
#pragma unroll
      for (int i = 0; i < 4; ++i) a4[i] = *(const float4*)&sA[tk * 4 + i][hh];
#pragma unroll
      for (int j = 0; j < 4; ++j) b4[j] = *(const float4*)&sB[tu * 4 + j][hh];
#pragma unroll
      for (int i = 0; i < 4; ++i)
#pragma unroll
        for (int j = 0; j < 4; ++j)
          acc[i][j] += a4[i].x * b4[j].x + a4[i].y * b4[j].y +
                       a4[i].z * b4[j].z + a4[i].w * b4[j].w;
    }
    __syncthreads();
  }
  const int k0 = kt * 64 + tk * 4;
#pragma unroll
  for (int i = 0; i < 4; ++i) {
    int k = k0 + i;
    if (k < NT) {
      float4 v = make_float4(acc[i][0], acc[i][1], acc[i][2], acc[i][3]);
      *(float4*)&scores[((size_t)b * NT + k) * 64 + tu * 4] = v;
    }
  }
}

// ---------------- K2b: per-(b,u,n) online max/sum over T with doc_mask ----------------
__global__ __launch_bounds__(256) void k2b_tstats(const float* __restrict__ scores,
                                                  const int* __restrict__ dm,
                                                  float* __restrict__ tmax,
                                                  float* __restrict__ tsum) {
  const int b = blockIdx.x / NN;
  const int n = blockIdx.x % NN;
  const int u = threadIdx.x & 63;
  const int tg = threadIdx.x >> 6;  // 0..3
  float m = -__builtin_inff(), s = 0.0f;
  for (int t = tg; t < TT; t += 4) {
    int dmv = dm[(b * NN + n) * TT + t];  // wave-uniform
    if (dmv) {
      float v = scores[((size_t)(b * NT) + n * TT + t) * 64 + u];
      if (v > m) { s = s * __expf(m - v) + 1.0f; m = v; }
      else s += __expf(v - m);
    }
  }
  __shared__ float sm[4][64], ss[4][64];
  sm[tg][u] = m; ss[tg][u] = s;
  __syncthreads();
  if (threadIdx.x < 64) {
    float M = sm[0][u];
#pragma unroll
    for (int i = 1; i < 4; ++i) M = fmaxf(M, sm[i][u]);
    float S = 0.0f;
#pragma unroll
    for (int i = 0; i < 4; ++i) {
      if (ss[i][u] > 0.0f) S += ss[i][u] * __expf(sm[i][u] - M);
    }
    tmax[(b * 64 + u) * NN + n] = M;
    tsum[(b * 64 + u) * NN + n] = S;
  }
}

// ---------------- K2c: fused in-place U-softmax + t-weight Pt (bf16) ----------------
// One wave per (b,k) row. Each exp computed exactly once.
__global__ __launch_bounds__(256) void k2c_softmax_pt(float* __restrict__ scores,
                                                      const int* __restrict__ qm,
                                                      const int* __restrict__ dm,
                                                      const float* __restrict__ tmax,
                                                      const float* __restrict__ tsum,
                                                      unsigned short* __restrict__ Pt) {
  const int row = blockIdx.x * 4 + (threadIdx.x >> 6);  // 0..47999
  const int u = threadIdx.x & 63;
  const int b = row / NT;
  const int k = row - b * NT;
  const int n = k / TT;
  const float s = scores[(size_t)row * 64 + u];
  // U-softmax (in place)
  const int m = qm[b * 64 + u];
  float v = m ? s : -__builtin_inff();
#pragma unroll
  for (int o = 32; o > 0; o >>= 1) v = fmaxf(v, __shfl_xor(v, o, 64));
  float e = m ? __expf(s - v) : 0.0f;
  float sum = e;
#pragma unroll
  for (int o = 32; o > 0; o >>= 1) sum += __shfl_xor(sum, o, 64);
  scores[(size_t)row * 64 + u] = (sum > 0.0f) ? (e / sum) : 0.0f;
  // t-softmax weight -> Pt (bf16)
  float w = 0.0f;
  if (dm[b * NT + k]) {  // dm is [B][N][T] flat = [B][NT]
    float S = tsum[(b * 64 + u) * NN + n];
    if (S > 0.0f) w = __expf(s - tmax[(b * 64 + u) * NN + n]) / S;
  }
  Pt[(size_t)row * 64 + u] = f2bf(w);
}

// ---------------- K3g: aggdoc GEMM: W[:,512:] += Pt^T * doc (split-k atomic) ----------------
__global__ __launch_bounds__(256) void k3g_aggdoc(const unsigned short* __restrict__ Pt,
                                                  const void* __restrict__ docv,
                                                  const int* __restrict__ flag,
                                                  float* __restrict__ W) {
  __shared__ float sP[32][72];
  __shared__ float sD[32][68];
  const int isf32 = *flag;
  const int b = blockIdx.z, hc = blockIdx.y, kc = blockIdx.x;  // (8,8,8)
  const int tid = threadIdx.x;
  const int th = tid & 15, tuq = tid >> 4;  // h = hc*64+th*4+j, u = tuq*4+i
  float acc[4][4] = {};
  const int k0base = kc * 750, kend = k0base + 750;
  for (int k0 = k0base; k0 < kend; k0 += 32) {
    const int kn = min(32, kend - k0);
    // stage Pt chunk: [32][64] bf16 -> f32
#pragma unroll
    for (int i = 0; i < 2; ++i) {
      int g = tid + 256 * i;  // 512 ushort4 groups
      int kk = g >> 4, c4 = (g & 15) * 4;
      float4 v = make_float4(0.f, 0.f, 0.f, 0.f);
      if (kk < kn) {
        ushort4 t4 = *(const ushort4*)&Pt[((size_t)(b * NT) + k0 + kk) * 64 + c4];
        v = make_float4(bf2f(t4.x), bf2f(t4.y), bf2f(t4.z), bf2f(t4.w));
      }
      *(float4*)&sP[kk][c4] = v;
    }
    // stage doc chunk: [32][64]
#pragma unroll
    for (int i = 0; i < 2; ++i) {
      int g = tid + 256 * i;
      int kk = g >> 4, c4 = (g & 15) * 4;
      float4 v = make_float4(0.f, 0.f, 0.f, 0.f);
      if (kk < kn) {
        size_t off = ((size_t)(b * NT) + k0 + kk) * HH + hc * 64 + c4;
        if (isf32) v = *(const float4*)((const float*)docv + off);
        else {
          ushort4 t4 = *(const ushort4*)((const unsigned short*)docv + off);
          v = make_float4(bf2f(t4.x), bf2f(t4.y), bf2f(t4.z), bf2f(t4.w));
        }
      }
      *(float4*)&sD[kk][c4] = v;
    }
    __syncthreads();
    for (int kk = 0; kk < kn; ++kk) {
      float4 w4 = *(const float4*)&sP[kk][tuq * 4];
      float4 d4 = *(const float4*)&sD[kk][th * 4];
      acc[0][0] += w4.x * d4.x; acc[0][1] += w4.x * d4.y; acc[0][2] += w4.x * d4.z; acc[0][3] += w4.x * d4.w;
      acc[1][0] += w4.y * d4.x; acc[1][1] += w4.y * d4.y; acc[1][2] += w4.y * d4.z; acc[1][3] += w4.y * d4.w;
      acc[2][0] += w4.z * d4.x; acc[2][1] += w4.z * d4.y; acc[2][2] += w4.z * d4.z; acc[2][3] += w4.z * d4.w;
      acc[3][0] += w4.w * d4.x; acc[3][1] += w4.w * d4.y; acc[3][2] += w4.w * d4.z; acc[3][3] += w4.w * d4.w;
    }
    __syncthreads();
  }
#pragma unroll
  for (int i = 0; i < 4; ++i) {
#pragma unroll
    for (int j = 0; j < 4; ++j) {
      size_t addr = ((size_t)(b * 64) + tuq * 4 + i) * 1024 + 512 + hc * 64 + th * 4 + j;
      atomicAdd(&W[addr], acc[i][j]);
    }
  }
}

// ---------------- fallback K2 (in-place U-softmax only) ----------------
__global__ __launch_bounds__(256) void k2_softmax_u(float* __restrict__ scores,
                                                    const int* __restrict__ qm) {
  const int row = blockIdx.x * 4 + (threadIdx.x >> 6);
  const int u = threadIdx.x & 63;
  const int b = row / NT;
  const float s = scores[(size_t)row * 64 + u];
  const int m = qm[b * 64 + u];
  float v = m ? s : -__builtin_inff();
#pragma unroll
  for (int o = 32; o > 0; o >>= 1) v = fmaxf(v, __shfl_xor(v, o, 64));
  float e = m ? __expf(s - v) : 0.0f;
  float sum = e;
#pragma unroll
  for (int o = 32; o > 0; o >>= 1) sum += __shfl_xor(sum, o, 64);
  scores[(size_t)row * 64 + u] = (sum > 0.0f) ? (e / sum) : 0.0f;
}

// ---------------- fallback K3 (original fused aggdoc) ----------------
__global__ __launch_bounds__(256) void k3_aggdoc(const float* __restrict__ scores,
                                                 const void* __restrict__ docv,
                                                 const int* __restrict__ dm,
                                                 const float* __restrict__ tmax,
                                                 const float* __restrict__ tsum,
                                                 const int* __restrict__ flag,
                                                 float* __restrict__ W) {
  __shared__ float wL[32][68];
  __shared__ float dL[32][68];
  const int isf32 = *flag;
  const int b = blockIdx.z, hc = blockIdx.y, kc = blockIdx.x;  // (16,8,8)
  const int tid = threadIdx.x;
  const int th = tid & 15, tuq = tid >> 4;
  float acc[4][4] = {};
  const int k0base = kc * 375, kend = k0base + 375;
  for (int k0 = k0base; k0 < kend; k0 += 32) {
    const int kn = min(32, kend - k0);
#pragma unroll
    for (int i = 0; i < 8; ++i) {
      int idx = tid + 256 * i;
      int kk = idx >> 6, uu = idx & 63;
      float w = 0.0f;
      if (kk < kn) {
        int k = k0 + kk;
        int n = k / TT;
        if (dm[b * NT + k]) {
          float S = tsum[(b * 64 + uu) * NN + n];
          if (S > 0.0f) {
            float M = tmax[(b * 64 + uu) * NN + n];
            w = __expf(scores[((size_t)(b * NT) + k) * 64 + uu] - M) / S;
          }
        }
      }
      wL[kk][uu] = w;
    }
#pragma unroll
    for (int i = 0; i < 2; ++i) {
      int g = tid + 256 * i;
      int kk = g >> 4, c4 = (g & 15) * 4;
      float4 v = make_float4(0.f, 0.f, 0.f, 0.f);
      if (kk < kn) {
        size_t off = ((size_t)(b * NT) + k0 + kk) * HH + hc * 64 + c4;
        if (isf32) v = *(const float4*)((const float*)docv + off);
        else {
          ushort4 t4 = *(const ushort4*)((const unsigned short*)docv + off);
          v = make_float4(bf2f(t4.x), bf2f(t4.y), bf2f(t4.z), bf2f(t4.w));
        }
      }
      *(float4*)&dL[kk][c4] = v;
    }
    __syncthreads();
    for (int kk = 0; kk < kn; ++kk) {
      float4 w4 = *(const float4*)&wL[kk][tuq * 4];
      float4 d4 = *(const float4*)&dL[kk][th * 4];
      acc[0][0] += w4.x * d4.x; acc[0][1] += w4.x * d4.y; acc[0][2] += w4.x * d4.z; acc[0][3] += w4.x * d4.w;
      acc[1][0] += w4.y * d4.x; acc[1][1] += w4.y * d4.y; acc[1][2] += w4.y * d4.z; acc[1][3] += w4.y * d4.w;
      acc[2][0] += w4.z * d4.x; acc[2][1] += w4.z * d4.y; acc[2][2] += w4.z * d4.z; acc[2][3] += w4.z * d4.w;
      acc[3][0] += w4.w * d4.x; acc[3][1] += w4.w * d4.y; acc[3][2] += w4.w * d4.z; acc[3][3] += w4.w * d4.w;
    }
    __syncthreads();
  }
#pragma unroll
  for (int i = 0; i < 4; ++i) {
#pragma unroll
    for (int j = 0; j < 4; ++j) {
      size_t addr = ((size_t)(b * 64) + tuq * 4 + i) * 1024 + 512 + hc * 64 + th * 4 + j;
      atomicAdd(&W[addr], acc[i][j]);
    }
  }
}

// ---------------- K4: out[b,k,h2] = sum_u attn[b,k,u] * W[b,u,h2] (64k x 128h tile) ----------------
__global__ __launch_bounds__(256) void k4_out(const float* __restrict__ attn,
                                              const float* __restrict__ W,
                                              const int* __restrict__ flag,
                                              void* __restrict__ outv) {
  __shared__ float sAt[64][68];
  __shared__ float sWt[64][132];
  const int isf32 = *flag;
  const int b = blockIdx.z;
  const int kt = blockIdx.x;  // 0..93
  const int ht = blockIdx.y;  // 0..7 (128 h2 each)
  const int tid = threadIdx.x;
  const int th2 = tid & 15, tkq = tid >> 4;
#pragma unroll
  for (int i = 0; i < 4; ++i) {
    int g = tid + 256 * i;  // 1024 float4 groups
    int row = g >> 4, c4 = (g & 15) * 4;
    int k = kt * 64 + row;
    float4 v = make_float4(0.f, 0.f, 0.f, 0.f);
    if (k < NT) v = *(const float4*)&attn[((size_t)(b * NT) + k) * 64 + c4];
    *(float4*)&sAt[row][c4] = v;
  }
#pragma unroll
  for (int i = 0; i < 8; ++i) {
    int g = tid + 256 * i;  // 2048 float4 groups: 64 rows x 32 groups
    int row = g >> 5, c4 = (g & 31) * 4;
    float4 w = *(const float4*)&W[((size_t)(b * 64) + row) * 1024 + ht * 128 + c4];
    *(float4*)&sWt[row][c4] = w;
  }
  __syncthreads();
  float acc[4][8] = {};
#pragma unroll 4
  for (int u = 0; u < 64; u += 4) {
    float a[4][4];
#pragma unroll
    for (int i = 0; i < 4; ++i)
      *(float4*)a[i] = *(const float4*)&sAt[tkq * 4 + i][u];
#pragma unroll
    for (int r = 0; r < 4; ++r) {
      float4 w0 = *(const float4*)&sWt[u + r][th2 * 4];
      float4 w1 = *(const float4*)&sWt[u + r][64 + th2 * 4];
#pragma unroll
      for (int i = 0; i < 4; ++i) {
        acc[i][0] += a[i][r] * w0.x; acc[i][1] += a[i][r] * w0.y;
        acc[i][2] += a[i][r] * w0.z; acc[i][3] += a[i][r] * w0.w;
        acc[i][4] += a[i][r] * w1.x; acc[i][5] += a[i][r] * w1.y;
        acc[i][6] += a[i][r] * w1.z; acc[i][7] += a[i][r] * w1.w;
      }
    }
  }
#pragma unroll
  for (int i = 0; i < 4; ++i) {
    int k = kt * 64 + tkq * 4 + i;
    if (k < NT) {
      size_t off = ((size_t)(b * NT) + k) * 1024 + ht * 128 + th2 * 4;
      if (isf32) {
        *(float4*)((float*)outv + off) = make_float4(acc[i][0], acc[i][1], acc[i][2], acc[i][3]);
        *(float4*)((float*)outv + off + 64) = make_float4(acc[i][4], acc[i][5], acc[i][6], acc[i][7]);
      } else {
        ushort4 o0, o1;
        o0.x = f2bf(acc[i][0]); o0.y = f2bf(acc[i][1]); o0.z = f2bf(acc[i][2]); o0.w = f2bf(acc[i][3]);
        o1.x = f2bf(acc[i][4]); o1.y = f2bf(acc[i][5]); o1.z = f2bf(acc[i][6]); o1.w = f2bf(acc[i][7]);
        *(ushort4*)((unsigned short*)outv + off) = o0;
        *(ushort4*)((unsigned short*)outv + off + 64) = o1;
      }
    }
  }
}

extern "C" void kernel_launch(void* const* d_in, const int* in_sizes, int n_in,
                              void* d_out, int out_size, void* d_ws, size_t ws_size,
                              hipStream_t stream) {
  const void* doc = d_in[0];               // [B][N][T][H]  f32 or bf16 (auto-detected)
  const void* q   = d_in[1];               // [B][U][H]
  const int* dmask = (const int*)d_in[2];  // int32 [B][N][T]
  const int* qmask = (const int*)d_in[3];  // int32 [B][U]

  float* ws = (float*)d_ws;
  float* scores = ws;                       // 3,072,000 (raw scores -> attn in-place)
  float* tmax   = ws + 3072000;             // 10,240
  float* tsum   = ws + 3082240;             // 10,240
  float* W      = ws + 3092480;             // 524,288
  int*   flag   = (int*)(ws + 3616768);     // 4 slots
  unsigned short* Pt = (unsigned short*)(ws + 3616772);  // 3,072,000 ushorts

  const size_t need_pt = (size_t)(3616772 + 1536000) * 4;  // 20.6 MB
  const bool pt_path = ws_size >= need_pt;

  kdetect<<<1, 256, 0, stream>>>((const unsigned short*)doc, flag);
  k0_init<<<2048, 256, 0, stream>>>(q, flag, W);
  k1_scores<<<dim3(94, 8), 256, 0, stream>>>(doc, q, flag, scores);
  k2b_tstats<<<160, 256, 0, stream>>>(scores, dmask, tmax, tsum);
  if (pt_path) {
    k2c_softmax_pt<<<12000, 256, 0, stream>>>(scores, qmask, dmask, tmax, tsum, Pt);
    k3g_aggdoc<<<dim3(8, 8, 8), 256, 0, stream>>>(Pt, doc, flag, W);
  } else {
    k3_aggdoc<<<dim3(16, 8, 8), 256, 0, stream>>>(scores, doc, dmask, tmax, tsum, flag, W);
    k2_softmax_u<<<12000, 256, 0, stream>>>(scores, qmask);
  }
  k4_out<<<dim3(94, 8, 8), 256, 0, stream>>>(scores, W, flag, d_out);
}